// Round 1
// 87.995 us; speedup vs baseline: 1.1357x; 1.1357x over previous
//
#include <hip/hip_runtime.h>
#include <math.h>

// PureCartesianE3Conv on MI355X — round 9.
// r8 post-mortem: k_edge 45.2us at VALUBusy 36.5% — latency-bound wave-lockstep,
// and 60% of its FMAs (MLP1+MLP2) compute h(length), a smooth 1D function.
// r9: (a) tabulate h = silu(silu(emb@Wf1)@Wf2) at 8192 length samples (2MB,
// L2-resident) built once in k_setup; k_edge keeps only interp + final 64x48
// matmul (one barrier, no Wf2 scalar stream). (b) geometry moves to k_scatter
// (once per edge, not 4x), which also writes v4/g destinations in node-CSR
// order (einv) so k_node becomes a fully coalesced streaming kernel.
// (c) k_init + k_pairtab + table-build fused into one k_setup launch.

#define NPAIR 100
#define SCHUNK 1024
#define TS 8192
#define NB_TAB (TS / 64)
#define LSCALE (8192.0f / 7.0f)
#define LSTEP  (7.0f / 8192.0f)

__device__ __forceinline__ float silu_acc(float x) {
    return x / (1.0f + expf(-x));   // precise: setup path only
}

// ---------------- setup: zero counters + pair table + radial h-table ----------------
__global__ __launch_bounds__(256) void k_setup(
    int nbinit, int N, int* __restrict__ nodecnt, int* __restrict__ paircnt,
    const float* __restrict__ emb_table, const float* __restrict__ Wa1,
    const float* __restrict__ ba1, const float* __restrict__ Wa2,
    const float* __restrict__ ba2,
    const float* __restrict__ Wf1, const float* __restrict__ bf1,
    const float* __restrict__ Wf2, const float* __restrict__ bf2,
    const float* __restrict__ Wf3, const float* __restrict__ bf3,
    float* __restrict__ M, float* __restrict__ bM, float* __restrict__ Htab)
{
    __shared__ float lds[64 * 64];   // 16 KB: pairtab carves 136 floats, table uses all
    int blk = blockIdx.x;
    int tid = threadIdx.x;

    if (blk < nbinit) {              // ---- init counters ----
        int i = blk * 256 + tid;
        if (i < N) nodecnt[i] = 0;
        if (blk == 0 && tid < NPAIR) paircnt[tid] = 0;
        return;
    }
    blk -= nbinit;

    if (blk < NPAIR) {               // ---- pair table (atom-MLP folded into Wf3) ----
        int p = blk, pa = p / 10, pb = p % 10;
        float* sh = lds;             // 128
        float* sP = lds + 128;       // 8
        if (tid < 128) {
            int row = (tid < 64) ? pa : pb;
            int j = tid & 63;
            float a = ba1[j];
#pragma unroll
            for (int k = 0; k < 16; ++k) a = fmaf(emb_table[row * 16 + k], Wa1[k * 64 + j], a);
            sh[tid] = silu_acc(a);
        }
        __syncthreads();
        if (tid < 8) {
            float aa = ba2[tid], ab = ba2[tid];
            for (int j = 0; j < 64; ++j) {
                aa = fmaf(sh[j], Wa2[j * 8 + tid], aa);
                ab = fmaf(sh[64 + j], Wa2[j * 8 + tid], ab);
            }
            sP[tid] = aa * ab;
        }
        __syncthreads();
        for (int base = tid; base < 3072; base += 256) {
            int h = base / 48;
            int j = base - h * 48;
            const float* wr = Wf3 + h * 1536 + (j >> 4) * 128 + (j & 15);
            float a = 0.0f;
#pragma unroll
            for (int c = 0; c < 8; ++c) a = fmaf(sP[c], wr[c * 16], a);
            M[p * 3072 + base] = a;
        }
        if (tid < 48) {
            const float* br = bf3 + (tid >> 4) * 128 + (tid & 15);
            float a = 0.0f;
#pragma unroll
            for (int c = 0; c < 8; ++c) a = fmaf(sP[c], br[c * 16], a);
            bM[p * 48 + tid] = a;
        }
        return;
    }
    blk -= NPAIR;

    // ---- radial table: Htab[s][0:64] = silu(silu(emb(len_s)@Wf1+bf1)@Wf2+bf2) ----
    // 64 samples per block, 4 waves j-sliced (same structure as r8's k_edge MLP).
    int w = __builtin_amdgcn_readfirstlane(tid >> 6);
    int lane = tid & 63;
    int s = blk * 64 + lane;
    float len = (float)s * LSTEP;
    float ek[8];
#pragma unroll
    for (int k = 0; k < 8; ++k) {
        float d = fmaf(len, 1.8f, -(float)(k + 1));
        ek[k] = expf(-d * d) * 2.5253813613805388f;   // sqrt(8)/1.12
    }
    float t[16];
    {
        const float* bq = bf1 + w * 16;
#pragma unroll
        for (int j = 0; j < 16; ++j) t[j] = bq[j];
#pragma unroll
        for (int k = 0; k < 8; ++k) {
            float e8 = ek[k];
            const float* wr = Wf1 + k * 64 + w * 16;
#pragma unroll
            for (int j = 0; j < 16; ++j) t[j] = fmaf(e8, wr[j], t[j]);
        }
#pragma unroll
        for (int j = 0; j < 16; ++j) lds[(w * 16 + j) * 64 + lane] = silu_acc(t[j]);
    }
    __syncthreads();
    float h2[16];
    {
        const float* bq = bf2 + w * 16;
#pragma unroll
        for (int j = 0; j < 16; ++j) h2[j] = bq[j];
    }
#pragma unroll 8
    for (int k = 0; k < 64; ++k) {
        float hk = lds[k * 64 + lane];
        const float* wr = Wf2 + k * 64 + w * 16;
#pragma unroll
        for (int j = 0; j < 16; ++j) h2[j] = fmaf(hk, wr[j], h2[j]);
    }
    float* tp = Htab + (size_t)s * 64 + w * 16;
#pragma unroll
    for (int j = 0; j < 16; ++j) tp[j] = silu_acc(h2[j]);
}

// ---------------- count: node degree + pair histogram (LDS) ----------------
__global__ __launch_bounds__(256) void k_count(
    const int* __restrict__ esrc, const int* __restrict__ edst,
    const int* __restrict__ Aarr, int E,
    int* __restrict__ nodecnt, int* __restrict__ paircnt)
{
    __shared__ int hist[NPAIR];
    int tid = threadIdx.x;
    if (tid < NPAIR) hist[tid] = 0;
    __syncthreads();
    int base = blockIdx.x * SCHUNK;
    int lim = min(base + SCHUNK, E);
    for (int e = base + tid; e < lim; e += 256) {
        int d = edst[e];
        atomicAdd(&nodecnt[d], 1);
        int p = Aarr[esrc[e]] * 10 + Aarr[d];
        atomicAdd(&hist[p], 1);
    }
    __syncthreads();
    if (tid < NPAIR && hist[tid] > 0) atomicAdd(&paircnt[tid], hist[tid]);
}

// ---------------- merged scan: block 0 = nodes, block 1 = pairs ----------------
__global__ __launch_bounds__(1024) void k_scan(
    const int* __restrict__ nodecnt, int N, int* __restrict__ row_off,
    int* __restrict__ ncur,
    const int* __restrict__ paircnt, int* __restrict__ pcur,
    int* __restrict__ b2p, int maxblk, int* __restrict__ eslot,
    float* __restrict__ geo)
{
    __shared__ int buf[1024];
    __shared__ int off[NPAIR + 1];
    int t = threadIdx.x;
    if (blockIdx.x == 0) {
        int CH = (N + 1023) / 1024;
        int start = t * CH;
        int end = min(start + CH, N);
        int s = 0;
        for (int i = start; i < end; ++i) s += nodecnt[i];
        buf[t] = s;
        __syncthreads();
        for (int o = 1; o < 1024; o <<= 1) {
            int y = (t >= o) ? buf[t - o] : 0;
            __syncthreads();
            buf[t] += y;
            __syncthreads();
        }
        int run = buf[t] - s;
        for (int i = start; i < end; ++i) {
            row_off[i] = run;
            ncur[i] = run;
            run += nodecnt[i];
        }
        if (t == 1023) row_off[N] = buf[1023];
    } else {
        if (t == 0) {
            int run = 0;
            for (int p = 0; p < NPAIR; ++p) { off[p] = run; run += (paircnt[p] + 63) >> 6; }
            off[NPAIR] = run;
        }
        __syncthreads();
        for (int b = t; b < maxblk; b += 1024) b2p[b] = -1;
        __syncthreads();
        if (t < NPAIR) {
            pcur[t] = off[t] * 64;
            for (int b = off[t]; b < off[t + 1]; ++b) b2p[b] = t;
            int s = off[t] * 64 + paircnt[t];   // padding tail only
            int e2 = off[t + 1] * 64;
            for (int q = s; q < e2; ++q) { eslot[q] = -1; geo[q] = 0.0f; }
        }
    }
}

// ---------------- scatter: slot sort + geometry + CSR inverse ----------------
__global__ __launch_bounds__(256) void k_scatter(
    const float* __restrict__ pos, const float* __restrict__ edge_shifts,
    const float* __restrict__ cell, const int* __restrict__ batch,
    const int* __restrict__ esrc, const int* __restrict__ edst,
    const int* __restrict__ Aarr, int E,
    int* __restrict__ ncur, int* __restrict__ pcur,
    int* __restrict__ eslot, int* __restrict__ einv,
    float* __restrict__ v4, float* __restrict__ geo)
{
    __shared__ int hist[NPAIR];
    __shared__ int gbase[NPAIR];
    __shared__ int cur[NPAIR];
    int tid = threadIdx.x;
    if (tid < NPAIR) { hist[tid] = 0; cur[tid] = 0; }
    __syncthreads();
    int base = blockIdx.x * SCHUNK;
    int s2v[4], pv[4];
#pragma unroll
    for (int i = 0; i < 4; ++i) {
        int e = base + tid + i * 256;
        if (e < E) {
            int d = edst[e];
            s2v[i] = atomicAdd(&ncur[d], 1);
            pv[i] = Aarr[esrc[e]] * 10 + Aarr[d];
            atomicAdd(&hist[pv[i]], 1);
        }
    }
    __syncthreads();
    if (tid < NPAIR && hist[tid] > 0) gbase[tid] = atomicAdd(&pcur[tid], hist[tid]);
    __syncthreads();
#pragma unroll
    for (int i = 0; i < 4; ++i) {
        int e = base + tid + i * 256;
        if (e < E) {
            int r = atomicAdd(&cur[pv[i]], 1);
            int slot = gbase[pv[i]] + r;
            eslot[slot] = e;
            einv[slot] = s2v[i];
            // geometry once per edge (r8 did this 4x per edge in k_edge)
            int src = esrc[e], dst = edst[e];
            int b = batch[src];
            float s0 = edge_shifts[e * 3 + 0];
            float s1 = edge_shifts[e * 3 + 1];
            float s2 = edge_shifts[e * 3 + 2];
            const float* cm = cell + b * 9;
            float ev0 = pos[dst * 3 + 0] - pos[src * 3 + 0] + s0 * cm[0] + s1 * cm[3] + s2 * cm[6];
            float ev1 = pos[dst * 3 + 1] - pos[src * 3 + 1] + s0 * cm[1] + s1 * cm[4] + s2 * cm[7];
            float ev2 = pos[dst * 3 + 2] - pos[src * 3 + 2] + s0 * cm[2] + s1 * cm[5] + s2 * cm[8];
            float len = sqrtf(ev0 * ev0 + ev1 * ev1 + ev2 * ev2);
            float inv = 1.0f / (len + 1e-12f);
            // v4 in node-CSR order (k_node streams it); geo in slot order (k_edge)
            reinterpret_cast<float4*>(v4)[s2v[i]] =
                make_float4(ev0 * inv, ev1 * inv, ev2 * inv, len);
            geo[slot] = len * LSCALE;
        }
    }
}

// ---------------- fused per-edge kernel: table interp + final matmul ----------------
__global__ __launch_bounds__(256, 6) void k_edge(
    const int* __restrict__ eslot, const int* __restrict__ b2p,
    const int* __restrict__ einv, const float* __restrict__ geo,
    const float* __restrict__ Htab,
    const float* __restrict__ M, const float* __restrict__ bM,
    float* __restrict__ gout)
{
    __shared__ float hbuf[64 * 64];  // 16 KB, [k][lane]
    int p = b2p[blockIdx.x];
    if (p < 0) return;
    p = __builtin_amdgcn_readfirstlane(p);
    int tid = threadIdx.x;
    int w = __builtin_amdgcn_readfirstlane(tid >> 6);  // wave id 0..3, SGPR
    int lane = tid & 63;
    int slot = blockIdx.x * 64 + lane;
    int ee = eslot[slot];
    bool act = ee >= 0;

    // ---- fill hbuf via table gather + linear interp (wave w fills k in [w*16,+16)) ----
    float u = geo[slot];                       // len * LSCALE (0 for padding)
    int i0 = (int)u;
    i0 = min(max(i0, 0), TS - 2);
    float frac = u - (float)i0;
    const float4* r0 = reinterpret_cast<const float4*>(Htab + (size_t)i0 * 64 + w * 16);
    float4 ta[4], tb[4];
#pragma unroll
    for (int i = 0; i < 4; ++i) { ta[i] = r0[i]; tb[i] = r0[i + 16]; }  // +16 f4 = next row
    float* hb = hbuf + (w * 16) * 64 + lane;
#pragma unroll
    for (int i = 0; i < 4; ++i) {
        hb[(4 * i + 0) * 64] = fmaf(frac, tb[i].x - ta[i].x, ta[i].x);
        hb[(4 * i + 1) * 64] = fmaf(frac, tb[i].y - ta[i].y, ta[i].y);
        hb[(4 * i + 2) * 64] = fmaf(frac, tb[i].z - ta[i].z, ta[i].z);
        hb[(4 * i + 3) * 64] = fmaf(frac, tb[i].w - ta[i].w, ta[i].w);
    }
    __syncthreads();

    // ---- final slice: g[j in w*12..+12) = bM + h @ M  (M wave-uniform s_load) ----
    float g[12];
    {
        const float* bq = bM + p * 48 + w * 12;
#pragma unroll
        for (int j = 0; j < 12; ++j) g[j] = bq[j];
    }
    const float* __restrict__ mp = M + p * 3072 + w * 12;
#pragma unroll 8
    for (int h = 0; h < 64; ++h) {
        float hv = hbuf[h * 64 + lane];
        const float* wr = mp + h * 48;
#pragma unroll
        for (int j = 0; j < 12; ++j) g[j] = fmaf(hv, wr[j], g[j]);
    }

    if (act) {
        int ci = einv[slot];                   // node-CSR position -> k_node streams g
        float4* gp = reinterpret_cast<float4*>(gout + (size_t)ci * 48 + w * 12);
#pragma unroll
        for (int i = 0; i < 3; ++i)
            gp[i] = make_float4(g[4 * i], g[4 * i + 1], g[4 * i + 2], g[4 * i + 3]);
    }
}

// ---------------- per-node aggregation: one wave per node, streaming reads ----------------
__global__ __launch_bounds__(256) void k_node(
    const int* __restrict__ row_off,
    const float* __restrict__ v4, const float* __restrict__ g,
    int N, float* __restrict__ out)
{
    int tid = threadIdx.x;
    int lane = tid & 63;
    int grp = lane >> 4;
    int o = lane & 15;
    int n = blockIdx.x * 4 + (tid >> 6);
    if (n >= N) return;
    int beg = row_off[n], end = row_off[n + 1];
    float a0 = 0.0f;
    float a1[3] = {0.0f, 0.0f, 0.0f};
    float a2[9] = {0.0f, 0.0f, 0.0f, 0.0f, 0.0f, 0.0f, 0.0f, 0.0f, 0.0f};
    for (int k = beg + grp; k < end; k += 4) {
        const float* ge = g + (size_t)k * 48;
        float g0 = ge[o];
        float g1 = ge[16 + o];
        float g2 = ge[32 + o];
        float4 vv = reinterpret_cast<const float4*>(v4)[k];
        float v[3] = {vv.x, vv.y, vv.z};
        a0 += g0;
#pragma unroll
        for (int d = 0; d < 3; ++d) a1[d] = fmaf(g1, v[d], a1[d]);
#pragma unroll
        for (int d1 = 0; d1 < 3; ++d1) {
            float gv = g2 * v[d1];
#pragma unroll
            for (int d2 = 0; d2 < 3; ++d2)
                a2[d1 * 3 + d2] = fmaf(gv, v[d2], a2[d1 * 3 + d2]);
        }
    }
#pragma unroll
    for (int m = 16; m <= 32; m <<= 1) {
        a0 += __shfl_xor(a0, m, 64);
#pragma unroll
        for (int d = 0; d < 3; ++d) a1[d] += __shfl_xor(a1[d], m, 64);
#pragma unroll
        for (int dd = 0; dd < 9; ++dd) a2[dd] += __shfl_xor(a2[dd], m, 64);
    }
    float cnt = (float)(end - beg);
    float invc = (cnt > 0.0f) ? (1.0f / cnt) : 1.0f;
    float* on = out + (size_t)n * 416;
    if (lane < 52)
        reinterpret_cast<float4*>(on + 208)[lane] = make_float4(0.f, 0.f, 0.f, 0.f);
    if (grp == 0) {
        on[o] = a0 * invc;
#pragma unroll
        for (int d = 0; d < 3; ++d) on[16 + o * 3 + d] = a1[d] * invc;
#pragma unroll
        for (int dd = 0; dd < 9; ++dd) on[64 + o * 9 + dd] = a2[dd] * invc;
    }
}

extern "C" void kernel_launch(void* const* d_in, const int* in_sizes, int n_in,
                              void* d_out, int out_size, void* d_ws, size_t ws_size,
                              hipStream_t stream)
{
    const float* pos         = (const float*)d_in[0];
    const float* edge_shifts = (const float*)d_in[1];
    const float* cell        = (const float*)d_in[2];
    const int*   Aarr        = (const int*)d_in[3];
    const int*   batch       = (const int*)d_in[4];
    const int*   esrc        = (const int*)d_in[5];
    const int*   edst        = (const int*)d_in[6];
    const float* emb_table   = (const float*)d_in[7];
    const float* Wa1         = (const float*)d_in[8];
    const float* ba1         = (const float*)d_in[9];
    const float* Wa2         = (const float*)d_in[10];
    const float* ba2         = (const float*)d_in[11];
    const float* Wf1         = (const float*)d_in[12];
    const float* bf1         = (const float*)d_in[13];
    const float* Wf2         = (const float*)d_in[14];
    const float* bf2         = (const float*)d_in[15];
    const float* Wf3         = (const float*)d_in[16];
    const float* bf3         = (const float*)d_in[17];

    int N = in_sizes[0] / 3;
    int E = in_sizes[5];
    int maxblk = (E + 63) / 64 + NPAIR;
    int nslot = maxblk * 64;
    int nhblk = (E + SCHUNK - 1) / SCHUNK;
    int nbinit = (N + 255) / 256;
    float* out = (float*)d_out;

    char* ws = (char*)d_ws;
    size_t off = 0;
    auto alloc = [&](size_t bytes) -> void* {
        void* p = ws + off;
        off += (bytes + 255) & ~(size_t)255;
        return p;
    };
    float* M       = (float*)alloc((size_t)NPAIR * 3072 * sizeof(float));
    float* bM      = (float*)alloc((size_t)NPAIR * 48 * sizeof(float));
    float* Htab    = (float*)alloc((size_t)TS * 64 * sizeof(float));
    int*   nodecnt = (int*)alloc((size_t)N * sizeof(int));
    int*   paircnt = (int*)alloc((size_t)NPAIR * sizeof(int));
    int*   rowoff  = (int*)alloc((size_t)(N + 1) * sizeof(int));
    int*   ncur    = (int*)alloc((size_t)N * sizeof(int));
    int*   pcur    = (int*)alloc((size_t)NPAIR * sizeof(int));
    int*   b2p     = (int*)alloc((size_t)maxblk * sizeof(int));
    int*   eslot   = (int*)alloc((size_t)nslot * sizeof(int));
    int*   einv    = (int*)alloc((size_t)nslot * sizeof(int));
    float* geo     = (float*)alloc((size_t)nslot * sizeof(float));
    float* v4      = (float*)alloc((size_t)nslot * 4 * sizeof(float));
    float* g       = (float*)alloc((size_t)nslot * 48 * sizeof(float));
    (void)ws_size; (void)n_in; (void)out_size;

    k_setup<<<nbinit + NPAIR + NB_TAB, 256, 0, stream>>>(
        nbinit, N, nodecnt, paircnt, emb_table, Wa1, ba1, Wa2, ba2,
        Wf1, bf1, Wf2, bf2, Wf3, bf3, M, bM, Htab);
    k_count<<<nhblk, 256, 0, stream>>>(esrc, edst, Aarr, E, nodecnt, paircnt);
    k_scan<<<2, 1024, 0, stream>>>(nodecnt, N, rowoff, ncur, paircnt, pcur, b2p, maxblk, eslot, geo);
    k_scatter<<<nhblk, 256, 0, stream>>>(pos, edge_shifts, cell, batch, esrc, edst, Aarr, E,
                                         ncur, pcur, eslot, einv, v4, geo);
    k_edge<<<maxblk, 256, 0, stream>>>(eslot, b2p, einv, geo, Htab, M, bM, g);
    k_node<<<(N + 3) / 4, 256, 0, stream>>>(rowoff, v4, g, N, out);
}